// Round 22
// baseline (224.527 us; speedup 1.0000x reference)
//
#include <hip/hip_runtime.h>
#include <hip/hip_bf16.h>

// Problem constants (fixed by reference): B=4, S=2048, DIN=DOUT=4096
constexpr int GM = 8192;   // B*S rows
constexpr int GN = 4096;   // DOUT
constexpr int GK = 4096;   // DIN

constexpr int BM = 256, BN = 256, BK = 64;    // BK in i8 elements (= bytes)
constexpr int NSTEP = GK / BK;                // 64 K-steps
constexpr int SLOT_BYTES = BM * BK;           // 16384 (A only)
constexpr int LDS_BYTES = 2 * SLOT_BYTES;     // 32768

constexpr int PX_BLOCKS = GM;                 // 8192 (1 block/row)
constexpr int PW_BLOCKS = (GN * GK / 16) / 256;  // 4096 (1 frag-slice/thread)

using bf16x8 = __attribute__((ext_vector_type(8))) __bf16;
using i32x4  = __attribute__((ext_vector_type(4))) int;

// ---- fused prep: rows -> per-row absmax i8 quantize; tail -> sign(w) i8
// pre-fragmented in MFMA order: Wf[((rt*64 + ks)*64 + lane)*16 + e] =
// sgn(w[rt*16 + (lane&15)][ks*64 + (lane>>4)*16 + e]) — one wave B-fragment
// (16 cols x 64 k) = ONE contiguous 1 KB block, loadable as dwordx4/lane. ----
__global__ __launch_bounds__(256) void prep_fused_i8(
    const float* __restrict__ x, const float* __restrict__ iscale,
    const float* __restrict__ w, signed char* __restrict__ A,
    signed char* __restrict__ Wf, float* __restrict__ alpha) {
  int b = blockIdx.x;
  int t = threadIdx.x;
  if (b < PX_BLOCKS) {
    // prep_x: one block per row; alpha[row] = rowmax/127; A = rint(x*s/alpha)
    int row = b;
    const float* xr = x + (size_t)row * GK;
    float v[16];
    float mx = 0.f;
#pragma unroll
    for (int p = 0; p < 4; ++p) {
      int idx = p * 1024 + t * 4;
      float4 xv = *(const float4*)(xr + idx);
      float4 sv = *(const float4*)(iscale + idx);
      float a0 = xv.x * sv.x, a1 = xv.y * sv.y, a2 = xv.z * sv.z, a3 = xv.w * sv.w;
      v[p * 4 + 0] = a0; v[p * 4 + 1] = a1; v[p * 4 + 2] = a2; v[p * 4 + 3] = a3;
      mx = fmaxf(mx, fmaxf(fmaxf(fabsf(a0), fabsf(a1)), fmaxf(fabsf(a2), fabsf(a3))));
    }
#pragma unroll
    for (int off = 32; off > 0; off >>= 1)
      mx = fmaxf(mx, __shfl_down(mx, off));
    __shared__ float rm[4];
    int wid = t >> 6, lane = t & 63;
    if (lane == 0) rm[wid] = mx;
    __syncthreads();
    float m = fmaxf(fmaxf(rm[0], rm[1]), fmaxf(rm[2], rm[3]));
    float inv = m > 0.f ? 127.f / m : 0.f;
    if (t == 0) alpha[row] = m * (1.f / 127.f);
#pragma unroll
    for (int p = 0; p < 4; ++p) {
      int idx = p * 1024 + t * 4;
      char4 q;
      int q0 = (int)rintf(v[p * 4 + 0] * inv);
      int q1 = (int)rintf(v[p * 4 + 1] * inv);
      int q2 = (int)rintf(v[p * 4 + 2] * inv);
      int q3 = (int)rintf(v[p * 4 + 3] * inv);
      q.x = (signed char)max(-127, min(127, q0));
      q.y = (signed char)max(-127, min(127, q1));
      q.z = (signed char)max(-127, min(127, q2));
      q.w = (signed char)max(-127, min(127, q3));
      *(char4*)(A + (size_t)row * GK + idx) = q;
    }
  } else {
    // prep_w: one 16-B fragment slice per thread. Reads 64 contiguous bytes
    // per thread; writes fully coalesced (consecutive lanes -> consecutive
    // 16-B slices).
    int T = (b - PX_BLOCKS) * 256 + t;      // 0 .. 1048575
    int lane = T & 63, ks = (T >> 6) & 63, rt = T >> 12;
    const float* src = w + (size_t)(rt * 16 + (lane & 15)) * GK
                         + ks * 64 + (lane >> 4) * 16;
    auto sg = [](float v) -> unsigned int {
      return v > 0.f ? 1u : (v < 0.f ? 0xFFu : 0u);
    };
    int4 o;
    unsigned int r[4];
#pragma unroll
    for (int qi = 0; qi < 4; ++qi) {
      float4 vv = *(const float4*)(src + qi * 4);
      r[qi] = sg(vv.x) | (sg(vv.y) << 8) | (sg(vv.z) << 16) | (sg(vv.w) << 24);
    }
    o.x = (int)r[0]; o.y = (int)r[1]; o.z = (int)r[2]; o.w = (int)r[3];
    *(int4*)(Wf + (size_t)T * 16) = o;
  }
}

// -------------------- GEMM (i8): C[m][n] = alpha_m * sum_k qA[m][k]*sgnW[n][k] ----
// B-DIRECT-FROM-GLOBAL structure. Root cause of the 1-block-per-CU plateau
// (R17-R21): combined register file = VGPR ~84 + acc AGPR 128 ~= 212/thread
// -> 2 waves/SIMD -> one block/CU; cross-block pipe overlap is unreachable,
// so the only lever is shrinking the within-block LDS term. B now bypasses
// LDS entirely: raw i8 fragments load global->reg from the pre-fragmented
// Wf (1 KB coalesced per wave, dwordx4/lane, feeds MFMA directly — no CVT),
// double-buffered ONE step ahead in parity-named sets (bvA even / bvB odd,
// rule 20). Loads issue at the TOP of the preceding step -> a full K-step
// (~2000 cyc >> L2 ~200 / HBM ~900) covers them before the end-of-step
// __syncthreads vmcnt(0) drain. Waves with equal wn read identical
// addresses (L1 broadcast); per-XCD B panel 2.1 MB + L3 backstop.
// LDS holds only A (2 x 16 KiB): per-block per-K-step LDS work drops
// 1920 -> ~900 cyc (stage 8 KB write + 64 b128 reads) vs MFMA 1307 cyc.
// Loop per K-step (zero inline asm, R19-style):
//   { STAGE_A(t+1 -> slot^1); LOADB(t+1 -> other set); 8 af ds_reads;
//     32 MFMA(af, bv[t&1]); __syncthreads(); }
// A-swizzle unchanged (0 conflicts R17-R21): 16-B chunk c of row r holds
// k-group c^((r>>1)&3), both sides. i8 16x16x64 A-fragment: row = l&15,
// k = (l>>4)*16 + e; C/D: col = lane&15, row = (lane>>4)*4 + r.
// Epilogue: h = alpha[row]*acc -> bf16 into 2nd half of each f32 row slot.
__device__ inline void gload16(const void* g, const void* l) {
  __builtin_amdgcn_global_load_lds(
      (const __attribute__((address_space(1))) void*)g,
      (__attribute__((address_space(3))) void*)l, 16, 0, 0);
}

__global__ __launch_bounds__(512, 2) void gemm_i8(
    const signed char* __restrict__ A, const signed char* __restrict__ Wf,
    const float* __restrict__ alpha, float* __restrict__ C) {
  extern __shared__ signed char lds8[];  // 2 slots x 16 KiB (A only)

  // Square XCD chunking (R3-R21; FETCH ~98 MB on i8)
  int bid = blockIdx.x;            // 0..511
  int x = bid & 7, idx = bid >> 3;
  int brow = ((x & 3) << 3) | (idx & 7);   // 0..31
  int bcol = ((x >> 2) << 3) | (idx >> 3); // 0..15

  int tid = threadIdx.x, wid = tid >> 6, lane = tid & 63;
  int wm = wid & 1, wn = wid >> 1;         // 2M x 4N waves
  int lrow = lane & 15, lkhi = lane >> 4;

  const signed char* Ab = A + (size_t)(brow * BM) * GK;
  // per-lane base into pre-fragmented Wf: frag (ni, step u) at
  // ((rt*64 + u)*64 + lane)*16, rt = bcol*16 + wn*4 + ni
  const signed char* Bw = Wf + ((size_t)(bcol * 16 + wn * 4) * 64 * 64 + lane) * 16;

  // read-side swizzled chunk (4 x 16-B chunks per 64-B row)
  int rchunk = lkhi ^ ((lrow >> 1) & 3);
  int avbase = (wm * 128 + lrow) * 64 + rchunk * 16;  // + mi*1024

  // stage-side: thread t covers row t>>2 (0..127), chunk t&3; source chunk
  // pre-permuted so LDS chunk c of row r holds k-group c^((r>>1)&3).
  // Row+128 (2nd issue) preserves (r>>1)&3, so the same gcol applies.
  int grow = tid >> 2;
  int gcol = ((tid & 3) ^ ((tid >> 3) & 3)) * 16;  // byte offset in 64-B window

  auto STAGE_A = [&](int kstep, int si) {
    const signed char* sA = Ab + (size_t)grow * GK + kstep * BK + gcol;
    const signed char* dA = lds8 + si * SLOT_BYTES + tid * 16;
    gload16(sA, dA);
    gload16(sA + (size_t)128 * GK, dA + 8192);
  };

  i32x4 bvA[4], bvB[4];  // B fragments, parity-named (even / odd steps)
  auto LOADB = [&](int u, i32x4 (&bv)[4]) {
#pragma unroll
    for (int ni = 0; ni < 4; ++ni)
      bv[ni] = *(const i32x4*)(Bw + ((size_t)ni * 64 + u) * 1024);
  };

  i32x4 acc[8][4] = {};

  // prologue: A(0) -> slot0; B(0) -> bvA
  STAGE_A(0, 0);
  LOADB(0, bvA);
  __syncthreads();

  for (int t = 0; t < NSTEP; t += 2) {
    // ===== even step t (slot0 parity t&1, bvA) =====
    {
      const signed char* sl = lds8 + (t & 1) * SLOT_BYTES;
      if (t + 1 < NSTEP) { STAGE_A(t + 1, (t + 1) & 1); LOADB(t + 1, bvB); }
      i32x4 af[8];
#pragma unroll
      for (int mi = 0; mi < 8; ++mi)
        af[mi] = *(const i32x4*)(sl + avbase + mi * 1024);
#pragma unroll
      for (int mi = 0; mi < 8; ++mi)
#pragma unroll
        for (int ni = 0; ni < 4; ++ni)
          acc[mi][ni] = __builtin_amdgcn_mfma_i32_16x16x64_i8(
              af[mi], bvA[ni], acc[mi][ni], 0, 0, 0);
      __syncthreads();  // stage/B visibility for t+1; WAR for slot overwrite
    }
    // ===== odd step t+1 (other slot, bvB) =====
    {
      const signed char* sl = lds8 + ((t + 1) & 1) * SLOT_BYTES;
      if (t + 2 < NSTEP) { STAGE_A(t + 2, (t + 2) & 1); LOADB(t + 2, bvA); }
      i32x4 af[8];
#pragma unroll
      for (int mi = 0; mi < 8; ++mi)
        af[mi] = *(const i32x4*)(sl + avbase + mi * 1024);
#pragma unroll
      for (int mi = 0; mi < 8; ++mi)
#pragma unroll
        for (int ni = 0; ni < 4; ++ni)
          acc[mi][ni] = __builtin_amdgcn_mfma_i32_16x16x64_i8(
              af[mi], bvB[ni], acc[mi][ni], 0, 0, 0);
      if (t + 2 < NSTEP) __syncthreads();
    }
  }

  // epilogue: h = alpha[row]*acc as bf16 into 2nd half of each f32 row slot.
  // C/D layout: col = lane&15, row = (lane>>4)*4 + r
  int crow0 = brow * BM + wm * 128;
  int ccol0 = bcol * BN + wn * 64;
  char* Cb = (char*)C;
#pragma unroll
  for (int mi = 0; mi < 8; ++mi)
#pragma unroll
    for (int ni = 0; ni < 4; ++ni) {
      int col = ccol0 + ni * 16 + lrow;
#pragma unroll
      for (int r = 0; r < 4; ++r) {
        int row = crow0 + mi * 16 + lkhi * 4 + r;
        float h = alpha[row] * (float)acc[mi][ni][r];
        *(__bf16*)(Cb + (size_t)row * 16384 + 8192 + col * 2) = (__bf16)h;
      }
    }
}

// ---------- fused out_scale/bias + LayerNorm: bf16 h (2nd half-slot) -> f32 ----------
__global__ __launch_bounds__(256) void ln_fuse(
    float* __restrict__ out, const float* __restrict__ os,
    const float* __restrict__ bs, const float* __restrict__ g,
    const float* __restrict__ be) {
  constexpr int N = GN;  // 4096
  int row = blockIdx.x;
  const __bf16* hr = (const __bf16*)((const char*)out + (size_t)row * 16384 + 8192);
  float* orow = out + (size_t)row * N;
  int t = threadIdx.x;

  float v[16];
  float sum = 0.f, ssq = 0.f;
#pragma unroll
  for (int c = 0; c < 2; ++c) {
    int idx = c * 2048 + t * 8;       // 8 bf16 per chunk, 2 chunks/thread
    bf16x8 hv = *(const bf16x8*)(hr + idx);
    float4 s0 = *(const float4*)(os + idx);
    float4 s1 = *(const float4*)(os + idx + 4);
    float4 b0 = *(const float4*)(bs + idx);
    float4 b1 = *(const float4*)(bs + idx + 4);
#pragma unroll
    for (int j = 0; j < 4; ++j) {
      float a = (float)hv[j] * (&s0.x)[j] + (&b0.x)[j];
      v[c * 8 + j] = a;
      sum += a; ssq += a * a;
    }
#pragma unroll
    for (int j = 0; j < 4; ++j) {
      float a = (float)hv[4 + j] * (&s1.x)[j] + (&b1.x)[j];
      v[c * 8 + 4 + j] = a;
      sum += a; ssq += a * a;
    }
  }

  // wave64 reduce
#pragma unroll
  for (int off = 32; off > 0; off >>= 1) {
    sum += __shfl_down(sum, off);
    ssq += __shfl_down(ssq, off);
  }
  __shared__ float rs[8];
  int wid = t >> 6, lane = t & 63;
  if (lane == 0) { rs[wid] = sum; rs[4 + wid] = ssq; }
  __syncthreads();   // also separates all h reads from the in-place writes
  sum = rs[0] + rs[1] + rs[2] + rs[3];
  ssq = rs[4] + rs[5] + rs[6] + rs[7];

  float mean = sum * (1.f / N);
  float var = ssq * (1.f / N) - mean * mean;
  float rstd = rsqrtf(var + 1e-5f);

#pragma unroll
  for (int c = 0; c < 2; ++c) {
    int idx = c * 2048 + t * 8;
    float4 g0 = *(const float4*)(g + idx);
    float4 g1 = *(const float4*)(g + idx + 4);
    float4 e0 = *(const float4*)(be + idx);
    float4 e1 = *(const float4*)(be + idx + 4);
    float4 o0, o1;
#pragma unroll
    for (int j = 0; j < 4; ++j) {
      (&o0.x)[j] = (v[c * 8 + j] - mean) * rstd * (&g0.x)[j] + (&e0.x)[j];
      (&o1.x)[j] = (v[c * 8 + 4 + j] - mean) * rstd * (&g1.x)[j] + (&e1.x)[j];
    }
    *(float4*)(orow + idx) = o0;
    *(float4*)(orow + idx + 4) = o1;
  }
}

extern "C" void kernel_launch(void* const* d_in, const int* in_sizes, int n_in,
                              void* d_out, int out_size, void* d_ws, size_t ws_size,
                              hipStream_t stream) {
  const float* x      = (const float*)d_in[0];  // [4,2048,4096]
  const float* w      = (const float*)d_in[1];  // [4096,4096]
  const float* iscale = (const float*)d_in[2];  // [4096]
  const float* oscale = (const float*)d_in[3];  // [4096]
  const float* bias   = (const float*)d_in[4];  // [4096]
  const float* gamma  = (const float*)d_in[5];  // [4096]
  const float* beta   = (const float*)d_in[6];  // [4096]
  float* out = (float*)d_out;                   // [8192,4096] f32

  signed char* Ai8 = (signed char*)d_ws;                         // 33.6 MB
  signed char* Wf  = (signed char*)d_ws + (size_t)GM * GK;       // 16.8 MB
  float* alpha = (float*)((char*)d_ws + (size_t)GM * GK + (size_t)GN * GK);  // 32 KB

  (void)hipFuncSetAttribute((const void*)gemm_i8,
                            hipFuncAttributeMaxDynamicSharedMemorySize, LDS_BYTES);

  prep_fused_i8<<<PX_BLOCKS + PW_BLOCKS, 256, 0, stream>>>(x, iscale, w, Ai8,
                                                           Wf, alpha);
  gemm_i8<<<(GM / BM) * (GN / BN), 512, LDS_BYTES, stream>>>(Ai8, Wf, alpha, out);
  ln_fuse<<<GM, 256, 0, stream>>>(out, oscale, bias, gamma, beta);
}